// Round 2
// baseline (5323.731 us; speedup 1.0000x reference)
//
#include <hip/hip_runtime.h>
#include <math.h>

// Problem constants
#define TT   2048
#define NHH  32
#define DQK  192   // DN + DR
#define DVV  128

// ---------------------------------------------------------------------------
// Generic fp32 GEMM: C[M,N] = A[M,K] * B[K,N].  M%128==0, K%16==0, N%4==0.
// 128x128 tile, 256 threads, 8x8 per thread (2x2 sub-blocks of 4).
// ---------------------------------------------------------------------------
__global__ __launch_bounds__(256) void gemm_f32(const float* __restrict__ A,
                                                const float* __restrict__ B,
                                                float* __restrict__ C,
                                                int M, int N, int K)
{
    __shared__ float As[16][132];   // transposed A tile [k][m], pad 132 keeps 16B align + 2-way banks
    __shared__ float Bs[16][128];   // B tile [k][n]
    const int tid = threadIdx.x;
    const int tx = tid & 15, ty = tid >> 4;
    const int bm = blockIdx.y * 128, bn = blockIdx.x * 128;

    float acc[8][8];
#pragma unroll
    for (int i = 0; i < 8; ++i)
#pragma unroll
        for (int j = 0; j < 8; ++j) acc[i][j] = 0.0f;

    for (int k0 = 0; k0 < K; k0 += 16) {
        // Stage A tile (128 rows x 16 k), transposed into As[k][m]
        {
            int f = tid;
#pragma unroll
            for (int it = 0; it < 2; ++it, f += 256) {
                int row = f >> 2, kq = (f & 3) << 2;
                float4 v = *(const float4*)(A + (size_t)(bm + row) * K + k0 + kq);
                As[kq + 0][row] = v.x; As[kq + 1][row] = v.y;
                As[kq + 2][row] = v.z; As[kq + 3][row] = v.w;
            }
        }
        // Stage B tile (16 k x 128 n)
        {
            int f = tid;
#pragma unroll
            for (int it = 0; it < 2; ++it, f += 256) {
                int row = f >> 5, cq = (f & 31) << 2;
                int gc = bn + cq;
                float4 v = make_float4(0.f, 0.f, 0.f, 0.f);
                if (gc < N) v = *(const float4*)(B + (size_t)(k0 + row) * N + gc);
                *(float4*)&Bs[row][cq] = v;
            }
        }
        __syncthreads();
#pragma unroll
        for (int kk = 0; kk < 16; ++kk) {
            float a[8], b[8];
            *(float4*)&a[0] = *(float4*)&As[kk][ty * 4];
            *(float4*)&a[4] = *(float4*)&As[kk][64 + ty * 4];
            *(float4*)&b[0] = *(float4*)&Bs[kk][tx * 4];
            *(float4*)&b[4] = *(float4*)&Bs[kk][64 + tx * 4];
#pragma unroll
            for (int i = 0; i < 8; ++i)
#pragma unroll
                for (int j = 0; j < 8; ++j)
                    acc[i][j] += a[i] * b[j];
        }
        __syncthreads();
    }
#pragma unroll
    for (int i = 0; i < 8; ++i) {
        int r = bm + ((i < 4) ? (ty * 4 + i) : (64 + ty * 4 + (i - 4)));
#pragma unroll
        for (int jh = 0; jh < 2; ++jh) {
            int c0 = bn + jh * 64 + tx * 4;
            if (c0 < N) {
                float4 v = make_float4(acc[i][jh * 4 + 0], acc[i][jh * 4 + 1],
                                       acc[i][jh * 4 + 2], acc[i][jh * 4 + 3]);
                *(float4*)(C + (size_t)r * N + c0) = v;
            }
        }
    }
}

// ---------------------------------------------------------------------------
// RMSNorm over dim=1536, in place.  One block per row, 256 threads x 6 elems.
// ---------------------------------------------------------------------------
__global__ __launch_bounds__(256) void rmsnorm1536(float* __restrict__ x,
                                                   const float* __restrict__ g)
{
    int row = blockIdx.x, tid = threadIdx.x;
    float* p = x + (size_t)row * 1536;
    float v[6]; float ssum = 0.f;
#pragma unroll
    for (int u = 0; u < 6; ++u) { v[u] = p[tid + 256 * u]; ssum += v[u] * v[u]; }
    __shared__ float red[256];
    red[tid] = ssum; __syncthreads();
    for (int s = 128; s > 0; s >>= 1) {
        if (tid < s) red[tid] += red[tid + s];
        __syncthreads();
    }
    float inv = rsqrtf(red[0] * (1.0f / 1536.0f) + 1e-6f);
#pragma unroll
    for (int u = 0; u < 6; ++u) p[tid + 256 * u] = v[u] * inv * g[tid + 256 * u];
}

// ---------------------------------------------------------------------------
// kv post: rmsnorm(kv[:, :512]) -> kv_cn ; rope(kv[:, 512:576], pos=row) -> k_pe
// One block per row (position == row index since positions = arange(T)).
// ---------------------------------------------------------------------------
__global__ __launch_bounds__(256) void kvpost(const float* __restrict__ kvraw,
                                              const float* __restrict__ g,
                                              float* __restrict__ kv_cn,
                                              float* __restrict__ k_pe)
{
    int row = blockIdx.x, tid = threadIdx.x;
    const float* src = kvraw + (size_t)row * 576;
    float v0 = src[tid], v1 = src[tid + 256];
    float ssum = v0 * v0 + v1 * v1;
    __shared__ float red[256];
    red[tid] = ssum; __syncthreads();
    for (int s = 128; s > 0; s >>= 1) {
        if (tid < s) red[tid] += red[tid + s];
        __syncthreads();
    }
    float inv = rsqrtf(red[0] * (1.0f / 512.0f) + 1e-6f);
    kv_cn[(size_t)row * 512 + tid]       = v0 * inv * g[tid];
    kv_cn[(size_t)row * 512 + tid + 256] = v1 * inv * g[tid + 256];
    if (tid < 32) {
        float x1 = src[512 + 2 * tid], x2 = src[512 + 2 * tid + 1];
        float fr = powf(10000.0f, -(float)tid * (1.0f / 32.0f));
        float f = (float)row * fr;
        float c = cosf(f), s = sinf(f);
        k_pe[(size_t)row * 64 + 2 * tid]     = x1 * c - x2 * s;
        k_pe[(size_t)row * 64 + 2 * tid + 1] = x2 * c + x1 * s;
    }
}

// ---------------------------------------------------------------------------
// RoPE on q_pe slice of q buffer [T, NH*192] (cols h*192+128 .. h*192+191).
// grid = T, block = 1024 (h = tid>>5, pair = tid&31), pos = t.
// ---------------------------------------------------------------------------
__global__ __launch_bounds__(1024) void qrope(float* __restrict__ q)
{
    int t = blockIdx.x;
    int h = threadIdx.x >> 5, i = threadIdx.x & 31;
    float* base = q + (size_t)t * 6144 + h * 192 + 128;
    float x1 = base[2 * i], x2 = base[2 * i + 1];
    float fr = powf(10000.0f, -(float)i * (1.0f / 32.0f));
    float f = (float)t * fr;
    float c = cosf(f), s = sinf(f);
    base[2 * i]     = x1 * c - x2 * s;
    base[2 * i + 1] = x2 * c + x1 * s;
}

// ---------------------------------------------------------------------------
// Causal attention, flash style.
// grid = (qt=32, h=32), block = 256 (16x16 threads).
// Q tile 64x192 in LDS; per k-tile: K 64x192 (XOR-swizzled), V 64x128 in LDS.
// S 4x4 per thread in regs; online softmax in-register via 16-lane shfl groups.
// O 4x8 per thread; attn out [T, NH*128].
// ---------------------------------------------------------------------------
__global__ __launch_bounds__(256) void attn_kernel(const float* __restrict__ qws,
                                                   const float* __restrict__ kvup,
                                                   const float* __restrict__ kpe,
                                                   float* __restrict__ attn)
{
    __shared__ float qs[64][196];      // q tile, +4 pad -> 2-way banks
    __shared__ float ks[64 * 192];     // k tile, 16B-block XOR swizzle on d
    __shared__ float vs[64][132];      // v tile
    __shared__ float ss[64][68];       // P tile

    const int h = blockIdx.y, qt = blockIdx.x;
    const int q0 = qt * 64;
    const int tid = threadIdx.x;
    const int tx = tid & 15, ty = tid >> 4;
    const float scale = 0.07216878364870322f;   // 1/sqrt(192)

    // load Q tile (rows q0..q0+63, 192 contiguous floats per (row,head))
    for (int f = tid; f < 64 * 48; f += 256) {
        int r = f / 48, db = f % 48;
        *(float4*)&qs[r][db * 4] =
            *(const float4*)(qws + (size_t)(q0 + r) * 6144 + h * 192 + db * 4);
    }

    float accO[4][8];
    float mrow[4], lrow[4];
#pragma unroll
    for (int i = 0; i < 4; ++i) {
        mrow[i] = -1e30f; lrow[i] = 0.f;
#pragma unroll
        for (int u = 0; u < 8; ++u) accO[i][u] = 0.f;
    }

    for (int kt = 0; kt <= qt; ++kt) {
        const int k0 = kt * 64;
        __syncthreads();   // protect ks/vs/ss from previous iteration's readers
        // stage K tile: d<128 from kv_up nope part, d>=128 from k_pe (head-shared)
        for (int f = tid; f < 64 * 48; f += 256) {
            int r = f / 48, db = f % 48;
            float4 v;
            if (db < 32)
                v = *(const float4*)(kvup + (size_t)(k0 + r) * 8192 + h * 256 + db * 4);
            else
                v = *(const float4*)(kpe + (size_t)(k0 + r) * 64 + (db - 32) * 4);
            int pb = db ^ ((r >> 2) & 7);
            *(float4*)&ks[r * 192 + pb * 4] = v;
        }
        // stage V tile
        for (int f = tid; f < 64 * 32; f += 256) {
            int r = f / 32, cb = f % 32;
            *(float4*)&vs[r][cb * 4] =
                *(const float4*)(kvup + (size_t)(k0 + r) * 8192 + h * 256 + 128 + cb * 4);
        }
        __syncthreads();

        // S = Q K^T (4x4 per thread)
        float s[4][4];
#pragma unroll
        for (int i = 0; i < 4; ++i)
#pragma unroll
            for (int j = 0; j < 4; ++j) s[i][j] = 0.f;

        for (int db = 0; db < 48; ++db) {
            float4 qv[4], kv4[4];
#pragma unroll
            for (int i = 0; i < 4; ++i)
                qv[i] = *(float4*)&qs[4 * ty + i][db * 4];
#pragma unroll
            for (int j = 0; j < 4; ++j) {
                int pb = db ^ (tx & 7);   // (4tx+j)>>2 == tx
                kv4[j] = *(float4*)&ks[(4 * tx + j) * 192 + pb * 4];
            }
#pragma unroll
            for (int i = 0; i < 4; ++i)
#pragma unroll
                for (int j = 0; j < 4; ++j)
                    s[i][j] += qv[i].x * kv4[j].x + qv[i].y * kv4[j].y +
                               qv[i].z * kv4[j].z + qv[i].w * kv4[j].w;
        }

        // scale + causal mask + in-register online softmax (16-lane groups)
#pragma unroll
        for (int i = 0; i < 4; ++i) {
            int qi = q0 + 4 * ty + i;
#pragma unroll
            for (int j = 0; j < 4; ++j) {
                int kj = k0 + 4 * tx + j;
                s[i][j] = (kj <= qi) ? s[i][j] * scale : -1e30f;
            }
            float rm = fmaxf(fmaxf(s[i][0], s[i][1]), fmaxf(s[i][2], s[i][3]));
#pragma unroll
            for (int msk = 1; msk <= 8; msk <<= 1)
                rm = fmaxf(rm, __shfl_xor(rm, msk));
            float mnew  = fmaxf(mrow[i], rm);
            float alpha = __expf(mrow[i] - mnew);
            float psum = 0.f;
#pragma unroll
            for (int j = 0; j < 4; ++j) {
                float p = __expf(s[i][j] - mnew);
                s[i][j] = p; psum += p;
            }
#pragma unroll
            for (int msk = 1; msk <= 8; msk <<= 1)
                psum += __shfl_xor(psum, msk);
            lrow[i] = lrow[i] * alpha + psum;
            mrow[i] = mnew;
#pragma unroll
            for (int u = 0; u < 8; ++u) accO[i][u] *= alpha;
#pragma unroll
            for (int j = 0; j < 4; ++j) ss[4 * ty + i][4 * tx + j] = s[i][j];
        }
        __syncthreads();

        // O += P V   (rows 4ty..4ty+3, cols {4tx..+3, 64+4tx..+3})
        for (int kb = 0; kb < 16; ++kb) {
            float4 p4[4];
#pragma unroll
            for (int i = 0; i < 4; ++i)
                p4[i] = *(float4*)&ss[4 * ty + i][kb * 4];
            float4 va[4], vb[4];
#pragma unroll
            for (int w = 0; w < 4; ++w) {
                va[w] = *(float4*)&vs[kb * 4 + w][tx * 4];
                vb[w] = *(float4*)&vs[kb * 4 + w][64 + tx * 4];
            }
#pragma unroll
            for (int i = 0; i < 4; ++i) {
                float pv[4] = { p4[i].x, p4[i].y, p4[i].z, p4[i].w };
#pragma unroll
                for (int w = 0; w < 4; ++w) {
                    accO[i][0] += pv[w] * va[w].x;
                    accO[i][1] += pv[w] * va[w].y;
                    accO[i][2] += pv[w] * va[w].z;
                    accO[i][3] += pv[w] * va[w].w;
                    accO[i][4] += pv[w] * vb[w].x;
                    accO[i][5] += pv[w] * vb[w].y;
                    accO[i][6] += pv[w] * vb[w].z;
                    accO[i][7] += pv[w] * vb[w].w;
                }
            }
        }
    }

    // epilogue: divide by l, write attn [T, NH*128]
#pragma unroll
    for (int i = 0; i < 4; ++i) {
        float invl = 1.0f / lrow[i];
        float* dst = attn + (size_t)(q0 + 4 * ty + i) * 4096 + h * 128 + 4 * tx;
        float4 o0 = make_float4(accO[i][0] * invl, accO[i][1] * invl,
                                accO[i][2] * invl, accO[i][3] * invl);
        float4 o1 = make_float4(accO[i][4] * invl, accO[i][5] * invl,
                                accO[i][6] * invl, accO[i][7] * invl);
        *(float4*)dst = o0;
        *(float4*)(dst + 64) = o1;
    }
}

// ---------------------------------------------------------------------------
extern "C" void kernel_launch(void* const* d_in, const int* in_sizes, int n_in,
                              void* d_out, int out_size, void* d_ws, size_t ws_size,
                              hipStream_t stream)
{
    (void)in_sizes; (void)n_in; (void)out_size; (void)ws_size;
    // d_in order: positions, hidden_states, w_qa, w_kva, g_qa, w_qb, g_kva, w_kvb, w_o
    const float* hs    = (const float*)d_in[1];
    const float* w_qa  = (const float*)d_in[2];
    const float* w_kva = (const float*)d_in[3];
    const float* g_qa  = (const float*)d_in[4];
    const float* w_qb  = (const float*)d_in[5];
    const float* g_kva = (const float*)d_in[6];
    const float* w_kvb = (const float*)d_in[7];
    const float* w_o   = (const float*)d_in[8];
    float* out = (float*)d_out;

    float* ws    = (float*)d_ws;
    float* q_c   = ws;                          // 2048*1536
    float* kvraw = q_c   + (size_t)2048 * 1536; // 2048*576
    float* kv_cn = kvraw + (size_t)2048 * 576;  // 2048*512
    float* k_pe  = kv_cn + (size_t)2048 * 512;  // 2048*64
    float* qbuf  = k_pe  + (size_t)2048 * 64;   // 2048*6144
    float* kvup  = qbuf  + (size_t)2048 * 6144; // 2048*8192
    float* attn  = kvup  + (size_t)2048 * 8192; // 2048*4096

    dim3 blk(256);
    // q_c = hs @ w_qa ; kv = hs @ w_kva
    gemm_f32<<<dim3(1536 / 128, 2048 / 128), blk, 0, stream>>>(hs, w_qa, q_c, 2048, 1536, 4096);
    gemm_f32<<<dim3((576 + 127) / 128, 2048 / 128), blk, 0, stream>>>(hs, w_kva, kvraw, 2048, 576, 4096);
    // rmsnorms + k_pe rope
    rmsnorm1536<<<2048, 256, 0, stream>>>(q_c, g_qa);
    kvpost<<<2048, 256, 0, stream>>>(kvraw, g_kva, kv_cn, k_pe);
    // q = q_c @ w_qb ; rope q_pe
    gemm_f32<<<dim3(6144 / 128, 2048 / 128), blk, 0, stream>>>(q_c, w_qb, qbuf, 2048, 6144, 1536);
    qrope<<<2048, 1024, 0, stream>>>(qbuf);
    // kv_up = kv_cn @ w_kvb
    gemm_f32<<<dim3(8192 / 128, 2048 / 128), blk, 0, stream>>>(kv_cn, w_kvb, kvup, 2048, 8192, 512);
    // attention
    attn_kernel<<<dim3(32, 32), blk, 0, stream>>>(qbuf, kvup, k_pe, attn);
    // out = attn @ w_o
    gemm_f32<<<dim3(4096 / 128, 2048 / 128), blk, 0, stream>>>(attn, w_o, out, 2048, 4096, 4096);
}

// Round 3
// 997.911 us; speedup vs baseline: 5.3349x; 5.3349x over previous
//
#include <hip/hip_runtime.h>
#include <math.h>

typedef __bf16 bf16;
typedef __bf16 bf16x8 __attribute__((ext_vector_type(8)));
typedef __bf16 bf16x4 __attribute__((ext_vector_type(4)));
typedef float  f32x4  __attribute__((ext_vector_type(4)));

#define AS1C(p) ((const __attribute__((address_space(1))) void*)(p))
#define AS3(p)  ((__attribute__((address_space(3))) void*)(p))

// ---------------------------------------------------------------------------
// bf16 MFMA GEMM, m97 structure: C[M,N] = A[M,K] * Bt[N,K]^T
// 128x128 tile, 4 waves (2x2), BK=32, global_load_lds 16B, 16x16x32 MFMA.
// Requires: M%128==0, K%32==0, Bt padded to gridDim.x*128 rows. Store guard col<N.
// ---------------------------------------------------------------------------
template<bool OUT_BF16>
__global__ __launch_bounds__(256) void gemm_bf16(const bf16* __restrict__ A,
                                                 const bf16* __restrict__ Bt,
                                                 void* __restrict__ Cv,
                                                 int M, int N, int K)
{
    __shared__ bf16 As[128 * 32];
    __shared__ bf16 Bs[128 * 32];
    const int tid = threadIdx.x;
    const int lane = tid & 63, wid = tid >> 6;
    const int lg = lane >> 4, ll = lane & 15;
    const int wr = wid >> 1, wc = wid & 1;
    const int bm = blockIdx.y * 128, bn = blockIdx.x * 128;

    f32x4 acc[4][4] = {};

    // staging: lane l of wave w covers row w*16 + (l>>2), 16B chunk (l&3)
    const int srow = wid * 16 + (lane >> 2);
    const int schk = (lane & 3) * 8;                 // elems
    const bf16* Ag  = A  + (size_t)(bm + srow) * K + schk;
    const bf16* Ag2 = Ag + (size_t)64 * K;
    const bf16* Bg  = Bt + (size_t)(bn + srow) * K + schk;
    const bf16* Bg2 = Bg + (size_t)64 * K;
    bf16* Al = As + srow * 32 + schk;                // == As + wid*1024B/2 + lane*8 elems
    bf16* Bl = Bs + srow * 32 + schk;

    for (int k0 = 0; k0 < K; k0 += 32) {
        __syncthreads();
        __builtin_amdgcn_global_load_lds(AS1C(Ag  + k0), AS3(Al),            16, 0, 0);
        __builtin_amdgcn_global_load_lds(AS1C(Ag2 + k0), AS3(Al + 64 * 32), 16, 0, 0);
        __builtin_amdgcn_global_load_lds(AS1C(Bg  + k0), AS3(Bl),            16, 0, 0);
        __builtin_amdgcn_global_load_lds(AS1C(Bg2 + k0), AS3(Bl + 64 * 32), 16, 0, 0);
        __syncthreads();

        bf16x8 af[4], bfr[4];
#pragma unroll
        for (int mi = 0; mi < 4; ++mi)
            af[mi] = *(const bf16x8*)(As + (wr * 64 + mi * 16 + ll) * 32 + lg * 8);
#pragma unroll
        for (int ni = 0; ni < 4; ++ni)
            bfr[ni] = *(const bf16x8*)(Bs + (wc * 64 + ni * 16 + ll) * 32 + lg * 8);
#pragma unroll
        for (int mi = 0; mi < 4; ++mi)
#pragma unroll
            for (int ni = 0; ni < 4; ++ni)
                acc[mi][ni] = __builtin_amdgcn_mfma_f32_16x16x32_bf16(
                    af[mi], bfr[ni], acc[mi][ni], 0, 0, 0);
    }

#pragma unroll
    for (int mi = 0; mi < 4; ++mi)
#pragma unroll
        for (int ni = 0; ni < 4; ++ni)
#pragma unroll
            for (int j = 0; j < 4; ++j) {
                int row = bm + wr * 64 + mi * 16 + lg * 4 + j;
                int col = bn + wc * 64 + ni * 16 + ll;
                if (col < N) {
                    float v = acc[mi][ni][j];
                    if (OUT_BF16) ((bf16*)Cv)[(size_t)row * N + col] = (bf16)v;
                    else          ((float*)Cv)[(size_t)row * N + col] = v;
                }
            }
}

// ---------------------------------------------------------------------------
// transpose + cast: src[R][C] f32 -> dst[Cpad][R] bf16 (zero rows for c>=C)
// grid (Cpad/32, R/32), 256 threads.
// ---------------------------------------------------------------------------
__global__ __launch_bounds__(256) void transpose_cast(const float* __restrict__ src,
                                                      bf16* __restrict__ dst,
                                                      int R, int C)
{
    __shared__ float t[32][33];
    const int bx = blockIdx.x * 32, by = blockIdx.y * 32;
    const int x = threadIdx.x & 31, y = threadIdx.x >> 5;
#pragma unroll
    for (int k = 0; k < 4; ++k) {
        int r = by + y + k * 8, c = bx + x;
        t[y + k * 8][x] = (c < C) ? src[(size_t)r * C + c] : 0.0f;
    }
    __syncthreads();
#pragma unroll
    for (int k = 0; k < 4; ++k) {
        int c = bx + y + k * 8, r = by + x;
        dst[(size_t)c * R + r] = (bf16)t[x][y + k * 8];
    }
}

// f32 -> bf16 flat cast. grid*256*4 == n exactly.
__global__ __launch_bounds__(256) void cast_f32_bf16(const float* __restrict__ src,
                                                     bf16* __restrict__ dst, int n)
{
    int i = (blockIdx.x * 256 + threadIdx.x) * 4;
    if (i < n) {
        float4 v = *(const float4*)(src + i);
        bf16x4 o = { (bf16)v.x, (bf16)v.y, (bf16)v.z, (bf16)v.w };
        *(bf16x4*)(dst + i) = o;
    }
}

// ---------------------------------------------------------------------------
// RMSNorm over 1536, f32 in -> bf16 out. One block/row.
// ---------------------------------------------------------------------------
__global__ __launch_bounds__(256) void rmsnorm1536_bf16(const float* __restrict__ x,
                                                        const float* __restrict__ g,
                                                        bf16* __restrict__ o)
{
    int row = blockIdx.x, tid = threadIdx.x;
    const float* p = x + (size_t)row * 1536;
    float v[6]; float ssum = 0.f;
#pragma unroll
    for (int u = 0; u < 6; ++u) { v[u] = p[tid + 256 * u]; ssum += v[u] * v[u]; }
    __shared__ float red[256];
    red[tid] = ssum; __syncthreads();
    for (int s = 128; s > 0; s >>= 1) {
        if (tid < s) red[tid] += red[tid + s];
        __syncthreads();
    }
    float inv = rsqrtf(red[0] * (1.0f / 1536.0f) + 1e-6f);
#pragma unroll
    for (int u = 0; u < 6; ++u)
        o[(size_t)row * 1536 + tid + 256 * u] = (bf16)(v[u] * inv * g[tid + 256 * u]);
}

// ---------------------------------------------------------------------------
// kv post: rmsnorm(kv[:, :512]) -> kv_cn bf16 ; rope(kv[:, 512:576]) -> k_pe bf16
// ---------------------------------------------------------------------------
__global__ __launch_bounds__(256) void kvpost(const float* __restrict__ kvraw,
                                              const float* __restrict__ g,
                                              bf16* __restrict__ kv_cn,
                                              bf16* __restrict__ k_pe)
{
    int row = blockIdx.x, tid = threadIdx.x;
    const float* src = kvraw + (size_t)row * 576;
    float v0 = src[tid], v1 = src[tid + 256];
    float ssum = v0 * v0 + v1 * v1;
    __shared__ float red[256];
    red[tid] = ssum; __syncthreads();
    for (int s = 128; s > 0; s >>= 1) {
        if (tid < s) red[tid] += red[tid + s];
        __syncthreads();
    }
    float inv = rsqrtf(red[0] * (1.0f / 512.0f) + 1e-6f);
    kv_cn[(size_t)row * 512 + tid]       = (bf16)(v0 * inv * g[tid]);
    kv_cn[(size_t)row * 512 + tid + 256] = (bf16)(v1 * inv * g[tid + 256]);
    if (tid < 32) {
        float x1 = src[512 + 2 * tid], x2 = src[512 + 2 * tid + 1];
        float fr = powf(10000.0f, -(float)tid * (1.0f / 32.0f));
        float f = (float)row * fr;
        float c, s; sincosf(f, &s, &c);
        k_pe[(size_t)row * 64 + 2 * tid]     = (bf16)(x1 * c - x2 * s);
        k_pe[(size_t)row * 64 + 2 * tid + 1] = (bf16)(x2 * c + x1 * s);
    }
}

// ---------------------------------------------------------------------------
// In-place on q bf16 [T][6144]: scale everything by 1/sqrt(192), rope the pe part.
// ---------------------------------------------------------------------------
__global__ __launch_bounds__(256) void qrope_scale(bf16* __restrict__ q)
{
    const float sc = 0.07216878364870322f;   // 1/sqrt(192)
    int t = blockIdx.x, tid = threadIdx.x;
    bf16* row = q + (size_t)t * 6144;
#pragma unroll
    for (int u = 0; u < 16; ++u) {           // 4096 nope elems
        int idx = tid + 256 * u;
        int col = (idx >> 7) * 192 + (idx & 127);
        row[col] = (bf16)((float)row[col] * sc);
    }
#pragma unroll
    for (int u = 0; u < 4; ++u) {            // 1024 pe pairs
        int pid = tid + 256 * u;
        int h = pid >> 5, i = pid & 31;
        int col = h * 192 + 128 + 2 * i;
        float x1 = (float)row[col], x2 = (float)row[col + 1];
        float fr = powf(10000.0f, -(float)i * (1.0f / 32.0f));
        float f = (float)t * fr;
        float c, s; sincosf(f, &s, &c);
        row[col]     = (bf16)((x1 * c - x2 * s) * sc);
        row[col + 1] = (bf16)((x2 * c + x1 * s) * sc);
    }
}

// ---------------------------------------------------------------------------
// MFMA flash attention. grid (qt=32, h=32), 256 threads (4 waves x 16 q-rows).
// Q pre-scaled bf16 [2048][6144]; KV=kvup bf16 [2048][8192]; KPE bf16 [2048][64].
// Per k-tile (64): K in LDS [64][200] (padded), V^T in LDS [128][72] (padded,
// k-fast staging -> conflict-free), P per-wave [16][72]. fp32 online softmax.
// ---------------------------------------------------------------------------
__global__ __launch_bounds__(256) void attn_mfma(const bf16* __restrict__ Q,
                                                 const bf16* __restrict__ KV,
                                                 const bf16* __restrict__ KPE,
                                                 bf16* __restrict__ O)
{
    __shared__ bf16 Ks[64][200];
    __shared__ bf16 Vt[128][72];
    __shared__ bf16 Ps[4][16][72];

    const int h = blockIdx.y, qt = blockIdx.x;
    const int q0 = qt * 64;
    const int tid = threadIdx.x;
    const int lane = tid & 63, wid = tid >> 6;
    const int lg = lane >> 4, ll = lane & 15;

    // Q fragments: 6 per wave (192 = 6*32), rows wid*16 + ll
    bf16x8 qf[6];
    {
        const bf16* qrow = Q + (size_t)(q0 + wid * 16 + ll) * 6144 + h * 192;
#pragma unroll
        for (int dk = 0; dk < 6; ++dk)
            qf[dk] = *(const bf16x8*)(qrow + dk * 32 + lg * 8);
    }

    f32x4 accO[8] = {};
    float m_r[4], l_r[4];
#pragma unroll
    for (int j = 0; j < 4; ++j) { m_r[j] = -INFINITY; l_r[j] = 0.f; }

    const int vsk  = tid & 63;      // V staging: lane-fast k
    const int vsq0 = tid >> 6;

    for (int kt = 0; kt <= qt; ++kt) {
        const int k0 = kt * 64;
        __syncthreads();
        // ---- stage K tile: wave wid handles rows wid*16..+15 -------------
        {
            int r = wid * 16 + (lane >> 2);
            int rg = lane & 3;
#pragma unroll
            for (int cb = 0; cb < 6; ++cb) {
                int c = cb * 4 + rg;                  // 16B chunk 0..23
                bf16x8 v;
                if (cb < 4)  // c<16: nope from kvup
                    v = *(const bf16x8*)(KV + (size_t)(k0 + r) * 8192 + h * 256 + c * 8);
                else         // pe from k_pe
                    v = *(const bf16x8*)(KPE + (size_t)(k0 + r) * 64 + (c - 16) * 8);
                *(bf16x8*)&Ks[r][c * 8] = v;
            }
        }
        // ---- stage V^T: k-fast map: 64 lanes = 64 k, vq walks ------------
#pragma unroll
        for (int i = 0; i < 8; ++i) {
            int v4 = (vsq0 + i * 4) * 4;              // 0..124
            bf16x4 v = *(const bf16x4*)(KV + (size_t)(k0 + vsk) * 8192 + h * 256 + 128 + v4);
#pragma unroll
            for (int jj = 0; jj < 4; ++jj)
                Vt[v4 + jj][vsk] = v[jj];
        }
        __syncthreads();

        // ---- S = Q K^T : D[q'][k'], q'=(lg*4+j), k'=ni*16+ll -------------
        f32x4 sacc[4] = {};
#pragma unroll
        for (int dk = 0; dk < 6; ++dk) {
#pragma unroll
            for (int ni = 0; ni < 4; ++ni) {
                bf16x8 kf = *(const bf16x8*)&Ks[ni * 16 + ll][dk * 32 + lg * 8];
                sacc[ni] = __builtin_amdgcn_mfma_f32_16x16x32_bf16(qf[dk], kf, sacc[ni], 0, 0, 0);
            }
        }

        // ---- online softmax (fp32, 16-lane-group reductions) -------------
        float sv[4][4];   // [ni][j]
        const bool diag = (kt == qt);
#pragma unroll
        for (int ni = 0; ni < 4; ++ni)
#pragma unroll
            for (int j = 0; j < 4; ++j) {
                float s = sacc[ni][j];
                if (diag) {
                    int qg = wid * 16 + lg * 4 + j;       // within tile (q0==k0)
                    int kg = ni * 16 + ll;
                    if (kg > qg) s = -3.0e38f;
                }
                sv[ni][j] = s;
            }
#pragma unroll
        for (int j = 0; j < 4; ++j) {
            float pm = fmaxf(fmaxf(sv[0][j], sv[1][j]), fmaxf(sv[2][j], sv[3][j]));
#pragma unroll
            for (int msk = 1; msk <= 8; msk <<= 1)
                pm = fmaxf(pm, __shfl_xor(pm, msk));
            float mn = fmaxf(m_r[j], pm);
            float al = __expf(m_r[j] - mn);
            float ps = 0.f;
#pragma unroll
            for (int ni = 0; ni < 4; ++ni) {
                float p = __expf(sv[ni][j] - mn);
                sv[ni][j] = p; ps += p;
            }
#pragma unroll
            for (int msk = 1; msk <= 8; msk <<= 1)
                ps += __shfl_xor(ps, msk);
            l_r[j] = l_r[j] * al + ps;
            m_r[j] = mn;
#pragma unroll
            for (int vt = 0; vt < 8; ++vt) accO[vt][j] *= al;
#pragma unroll
            for (int ni = 0; ni < 4; ++ni)
                Ps[wid][lg * 4 + j][ni * 16 + ll] = (bf16)sv[ni][j];
        }

        // ---- O += P V ----------------------------------------------------
        bf16x8 pa[2];
#pragma unroll
        for (int kb = 0; kb < 2; ++kb)
            pa[kb] = *(const bf16x8*)&Ps[wid][ll][kb * 32 + lg * 8];
#pragma unroll
        for (int vt = 0; vt < 8; ++vt) {
#pragma unroll
            for (int kb = 0; kb < 2; ++kb) {
                bf16x8 vf = *(const bf16x8*)&Vt[vt * 16 + ll][kb * 32 + lg * 8];
                accO[vt] = __builtin_amdgcn_mfma_f32_16x16x32_bf16(pa[kb], vf, accO[vt], 0, 0, 0);
            }
        }
    }

    // ---- epilogue: /= l, write bf16 to attn [2048][4096] -----------------
    float inv[4];
#pragma unroll
    for (int j = 0; j < 4; ++j) inv[j] = 1.0f / l_r[j];
#pragma unroll
    for (int vt = 0; vt < 8; ++vt)
#pragma unroll
        for (int j = 0; j < 4; ++j) {
            int row = q0 + wid * 16 + lg * 4 + j;
            O[(size_t)row * 4096 + h * 128 + vt * 16 + ll] = (bf16)(accO[vt][j] * inv[j]);
        }
}

// ---------------------------------------------------------------------------
extern "C" void kernel_launch(void* const* d_in, const int* in_sizes, int n_in,
                              void* d_out, int out_size, void* d_ws, size_t ws_size,
                              hipStream_t stream)
{
    (void)in_sizes; (void)n_in; (void)out_size; (void)ws_size;
    const float* hs    = (const float*)d_in[1];
    const float* w_qa  = (const float*)d_in[2];
    const float* w_kva = (const float*)d_in[3];
    const float* g_qa  = (const float*)d_in[4];
    const float* w_qb  = (const float*)d_in[5];
    const float* g_kva = (const float*)d_in[6];
    const float* w_kvb = (const float*)d_in[7];
    const float* w_o   = (const float*)d_in[8];
    float* out = (float*)d_out;

    // ---- workspace layout (bytes). qfin aliases [hsb|wqaT]; attnb aliases
    // [q_c|kvraw] — both dead by the time the alias is written. ------------
    char* w = (char*)d_ws;
    bf16* hsb   = (bf16*)w;                     w += (size_t)2048 * 4096 * 2;   // 16.78M
    bf16* wqaT  = (bf16*)w;                     w += (size_t)1536 * 4096 * 2;   // 12.58M
    bf16* wkvaT = (bf16*)w;                     w += (size_t)640  * 4096 * 2;   //  5.24M
    bf16* wqbT  = (bf16*)w;                     w += (size_t)6144 * 1536 * 2;   // 18.87M
    bf16* wkvbT = (bf16*)w;                     w += (size_t)8192 * 512  * 2;   //  8.39M
    bf16* woT   = (bf16*)w;                     w += (size_t)4096 * 4096 * 2;   // 33.55M
    float* q_c  = (float*)w;                    w += (size_t)2048 * 1536 * 4;   // 12.58M
    float* kvraw= (float*)w;                    w += (size_t)2048 * 576  * 4;   //  4.72M
    bf16* q_cn  = (bf16*)w;                     w += (size_t)2048 * 1536 * 2;   //  6.29M
    bf16* kv_cn = (bf16*)w;                     w += (size_t)2048 * 512  * 2;   //  2.10M
    bf16* k_pe  = (bf16*)w;                     w += (size_t)2048 * 64   * 2;   //  0.26M
    bf16* kvup  = (bf16*)w;                     w += (size_t)2048 * 8192 * 2;   // 33.55M
    bf16* qfin  = hsb;                          // 25.17M into 29.36M  (alias)
    bf16* attnb = (bf16*)q_c;                   // 16.78M into 17.30M  (alias)

    dim3 blk(256);
    // casts + weight transposes
    cast_f32_bf16<<<8192, blk, 0, stream>>>(hs, hsb, 2048 * 4096);
    transpose_cast<<<dim3(48, 128),  blk, 0, stream>>>(w_qa,  wqaT,  4096, 1536);
    transpose_cast<<<dim3(20, 128),  blk, 0, stream>>>(w_kva, wkvaT, 4096, 576);
    transpose_cast<<<dim3(192, 48),  blk, 0, stream>>>(w_qb,  wqbT,  1536, 6144);
    transpose_cast<<<dim3(256, 16),  blk, 0, stream>>>(w_kvb, wkvbT, 512,  8192);
    transpose_cast<<<dim3(128, 128), blk, 0, stream>>>(w_o,   woT,   4096, 4096);

    // q_c = hs @ w_qa (f32 out) ; kvraw = hs @ w_kva (f32 out)
    gemm_bf16<false><<<dim3(12, 16), blk, 0, stream>>>(hsb, wqaT,  q_c,   2048, 1536, 4096);
    gemm_bf16<false><<<dim3(5,  16), blk, 0, stream>>>(hsb, wkvaT, kvraw, 2048, 576,  4096);

    rmsnorm1536_bf16<<<2048, blk, 0, stream>>>(q_c, g_qa, q_cn);
    kvpost<<<2048, blk, 0, stream>>>(kvraw, g_kva, kv_cn, k_pe);

    // q = q_cn @ w_qb (bf16 out, then rope+scale in place)
    gemm_bf16<true><<<dim3(48, 16), blk, 0, stream>>>(q_cn, wqbT, qfin, 2048, 6144, 1536);
    qrope_scale<<<2048, blk, 0, stream>>>(qfin);

    // kv_up = kv_cn @ w_kvb (bf16 out)
    gemm_bf16<true><<<dim3(64, 16), blk, 0, stream>>>(kv_cn, wkvbT, kvup, 2048, 8192, 512);

    // attention
    attn_mfma<<<dim3(32, 32), blk, 0, stream>>>(qfin, kvup, k_pe, attnb);

    // out = attn @ w_o (f32 out)
    gemm_bf16<false><<<dim3(32, 16), blk, 0, stream>>>(attnb, woT, out, 2048, 4096, 4096);
}

// Round 4
// 817.153 us; speedup vs baseline: 6.5150x; 1.2212x over previous
//
#include <hip/hip_runtime.h>
#include <math.h>

typedef __bf16 bf16;
typedef __bf16 bf16x8 __attribute__((ext_vector_type(8)));
typedef __bf16 bf16x4 __attribute__((ext_vector_type(4)));
typedef float  f32x4  __attribute__((ext_vector_type(4)));

#define AS1C(p) ((const __attribute__((address_space(1))) void*)(p))
#define AS3(p)  ((__attribute__((address_space(3))) void*)(p))

// ---------------------------------------------------------------------------
// bf16 MFMA GEMM, m97 structure: C[M,N] = A[M,K] * Bt[N,K]^T
// 128x128 tile, 4 waves (2x2), BK=32, global_load_lds 16B, 16x16x32 MFMA.
// MODE: 0 = f32 out, 1 = bf16 out, 2 = kvup split (even N-blocks -> row-major
// bf16 C; odd N-blocks are V columns -> store transposed to VT[h*128+dv][t]).
// ---------------------------------------------------------------------------
template<int MODE>
__global__ __launch_bounds__(256) void gemm_bf16(const bf16* __restrict__ A,
                                                 const bf16* __restrict__ Bt,
                                                 void* __restrict__ Cv,
                                                 bf16* __restrict__ VT,
                                                 int M, int N, int K)
{
    __shared__ bf16 As[128 * 32];
    __shared__ bf16 Bs[128 * 32];
    const int tid = threadIdx.x;
    const int lane = tid & 63, wid = tid >> 6;
    const int lg = lane >> 4, ll = lane & 15;
    const int wr = wid >> 1, wc = wid & 1;
    const int bm = blockIdx.y * 128, bn = blockIdx.x * 128;

    f32x4 acc[4][4] = {};

    const int srow = wid * 16 + (lane >> 2);
    const int schk = (lane & 3) * 8;
    const bf16* Ag  = A  + (size_t)(bm + srow) * K + schk;
    const bf16* Ag2 = Ag + (size_t)64 * K;
    const bf16* Bg  = Bt + (size_t)(bn + srow) * K + schk;
    const bf16* Bg2 = Bg + (size_t)64 * K;
    bf16* Al = As + srow * 32 + schk;
    bf16* Bl = Bs + srow * 32 + schk;

    for (int k0 = 0; k0 < K; k0 += 32) {
        __syncthreads();
        __builtin_amdgcn_global_load_lds(AS1C(Ag  + k0), AS3(Al),            16, 0, 0);
        __builtin_amdgcn_global_load_lds(AS1C(Ag2 + k0), AS3(Al + 64 * 32), 16, 0, 0);
        __builtin_amdgcn_global_load_lds(AS1C(Bg  + k0), AS3(Bl),            16, 0, 0);
        __builtin_amdgcn_global_load_lds(AS1C(Bg2 + k0), AS3(Bl + 64 * 32), 16, 0, 0);
        __syncthreads();

        bf16x8 af[4], bfr[4];
#pragma unroll
        for (int mi = 0; mi < 4; ++mi)
            af[mi] = *(const bf16x8*)(As + (wr * 64 + mi * 16 + ll) * 32 + lg * 8);
#pragma unroll
        for (int ni = 0; ni < 4; ++ni)
            bfr[ni] = *(const bf16x8*)(Bs + (wc * 64 + ni * 16 + ll) * 32 + lg * 8);
#pragma unroll
        for (int mi = 0; mi < 4; ++mi)
#pragma unroll
            for (int ni = 0; ni < 4; ++ni)
                acc[mi][ni] = __builtin_amdgcn_mfma_f32_16x16x32_bf16(
                    af[mi], bfr[ni], acc[mi][ni], 0, 0, 0);
    }

    const bool vsplit = (MODE == 2) && (blockIdx.x & 1);
    const int hh = bn >> 8;
#pragma unroll
    for (int mi = 0; mi < 4; ++mi)
#pragma unroll
        for (int ni = 0; ni < 4; ++ni)
#pragma unroll
            for (int j = 0; j < 4; ++j) {
                int row = bm + wr * 64 + mi * 16 + lg * 4 + j;
                int cl  = wc * 64 + ni * 16 + ll;
                int col = bn + cl;
                float v = acc[mi][ni][j];
                if (MODE == 2) {
                    if (vsplit) VT[(size_t)(hh * 128 + cl) * 2048 + row] = (bf16)v;
                    else        ((bf16*)Cv)[(size_t)row * N + col] = (bf16)v;
                } else if (col < N) {
                    if (MODE == 1) ((bf16*)Cv)[(size_t)row * N + col] = (bf16)v;
                    else           ((float*)Cv)[(size_t)row * N + col] = v;
                }
            }
}

// ---------------------------------------------------------------------------
// transpose + cast: src[R][C] f32 -> dst[Cpad][R] bf16 (zero rows for c>=C)
// ---------------------------------------------------------------------------
__global__ __launch_bounds__(256) void transpose_cast(const float* __restrict__ src,
                                                      bf16* __restrict__ dst,
                                                      int R, int C)
{
    __shared__ float t[32][33];
    const int bx = blockIdx.x * 32, by = blockIdx.y * 32;
    const int x = threadIdx.x & 31, y = threadIdx.x >> 5;
#pragma unroll
    for (int k = 0; k < 4; ++k) {
        int r = by + y + k * 8, c = bx + x;
        t[y + k * 8][x] = (c < C) ? src[(size_t)r * C + c] : 0.0f;
    }
    __syncthreads();
#pragma unroll
    for (int k = 0; k < 4; ++k) {
        int c = bx + y + k * 8, r = by + x;
        dst[(size_t)c * R + r] = (bf16)t[x][y + k * 8];
    }
}

__global__ __launch_bounds__(256) void cast_f32_bf16(const float* __restrict__ src,
                                                     bf16* __restrict__ dst, int n)
{
    int i = (blockIdx.x * 256 + threadIdx.x) * 4;
    if (i < n) {
        float4 v = *(const float4*)(src + i);
        bf16x4 o = { (bf16)v.x, (bf16)v.y, (bf16)v.z, (bf16)v.w };
        *(bf16x4*)(dst + i) = o;
    }
}

// ---------------------------------------------------------------------------
__global__ __launch_bounds__(256) void rmsnorm1536_bf16(const float* __restrict__ x,
                                                        const float* __restrict__ g,
                                                        bf16* __restrict__ o)
{
    int row = blockIdx.x, tid = threadIdx.x;
    const float* p = x + (size_t)row * 1536;
    float v[6]; float ssum = 0.f;
#pragma unroll
    for (int u = 0; u < 6; ++u) { v[u] = p[tid + 256 * u]; ssum += v[u] * v[u]; }
    __shared__ float red[256];
    red[tid] = ssum; __syncthreads();
    for (int s = 128; s > 0; s >>= 1) {
        if (tid < s) red[tid] += red[tid + s];
        __syncthreads();
    }
    float inv = rsqrtf(red[0] * (1.0f / 1536.0f) + 1e-6f);
#pragma unroll
    for (int u = 0; u < 6; ++u)
        o[(size_t)row * 1536 + tid + 256 * u] = (bf16)(v[u] * inv * g[tid + 256 * u]);
}

// ---------------------------------------------------------------------------
__global__ __launch_bounds__(256) void kvpost(const float* __restrict__ kvraw,
                                              const float* __restrict__ g,
                                              bf16* __restrict__ kv_cn,
                                              bf16* __restrict__ k_pe)
{
    int row = blockIdx.x, tid = threadIdx.x;
    const float* src = kvraw + (size_t)row * 576;
    float v0 = src[tid], v1 = src[tid + 256];
    float ssum = v0 * v0 + v1 * v1;
    __shared__ float red[256];
    red[tid] = ssum; __syncthreads();
    for (int s = 128; s > 0; s >>= 1) {
        if (tid < s) red[tid] += red[tid + s];
        __syncthreads();
    }
    float inv = rsqrtf(red[0] * (1.0f / 512.0f) + 1e-6f);
    kv_cn[(size_t)row * 512 + tid]       = (bf16)(v0 * inv * g[tid]);
    kv_cn[(size_t)row * 512 + tid + 256] = (bf16)(v1 * inv * g[tid + 256]);
    if (tid < 32) {
        float x1 = src[512 + 2 * tid], x2 = src[512 + 2 * tid + 1];
        float fr = powf(10000.0f, -(float)tid * (1.0f / 32.0f));
        float f = (float)row * fr;
        float c, s; sincosf(f, &s, &c);
        k_pe[(size_t)row * 64 + 2 * tid]     = (bf16)(x1 * c - x2 * s);
        k_pe[(size_t)row * 64 + 2 * tid + 1] = (bf16)(x2 * c + x1 * s);
    }
}

// ---------------------------------------------------------------------------
__global__ __launch_bounds__(256) void qrope_scale(bf16* __restrict__ q)
{
    const float sc = 0.07216878364870322f;   // 1/sqrt(192)
    int t = blockIdx.x, tid = threadIdx.x;
    bf16* row = q + (size_t)t * 6144;
#pragma unroll
    for (int u = 0; u < 16; ++u) {
        int idx = tid + 256 * u;
        int col = (idx >> 7) * 192 + (idx & 127);
        row[col] = (bf16)((float)row[col] * sc);
    }
#pragma unroll
    for (int u = 0; u < 4; ++u) {
        int pid = tid + 256 * u;
        int h = pid >> 5, i = pid & 31;
        int col = h * 192 + 128 + 2 * i;
        float x1 = (float)row[col], x2 = (float)row[col + 1];
        float fr = powf(10000.0f, -(float)i * (1.0f / 32.0f));
        float f = (float)t * fr;
        float c, s; sincosf(f, &s, &c);
        row[col]     = (bf16)((x1 * c - x2 * s) * sc);
        row[col + 1] = (bf16)((x2 * c + x1 * s) * sc);
    }
}

// ---------------------------------------------------------------------------
// MFMA flash attention, QBLK=128 (8 waves), KVBLK=64, T14 reg-staged pipeline,
// XOR-swizzled LDS (16B chunk ^ (row&7)).
// grid (16, 32): qtb = 15 - bx (longest-first), h = by.  512 threads.
// Q pre-scaled bf16 [2048][6144]; KV row-major k_nope slices [2048][8192];
// KPE [2048][64]; VT transposed V [32*128][2048].
// ---------------------------------------------------------------------------
__global__ __launch_bounds__(512) void attn_mfma(const bf16* __restrict__ Q,
                                                 const bf16* __restrict__ KV,
                                                 const bf16* __restrict__ KPE,
                                                 const bf16* __restrict__ VT,
                                                 bf16* __restrict__ O)
{
    __shared__ bf16 knS[64 * 128];    // K nope tile  [k][d<128]
    __shared__ bf16 kpS[64 * 64];     // K pe tile    [k][d-128]
    __shared__ bf16 vtS[128 * 64];    // V^T tile     [dv][k]
    __shared__ bf16 psS[8 * 16 * 88]; // P per wave   [wid][q][k], stride 88

    const int h = blockIdx.y;
    const int qtb = 15 - blockIdx.x;
    const int q0 = qtb * 128;
    const int tid = threadIdx.x;
    const int lane = tid & 63, wid = tid >> 6;
    const int lg = lane >> 4, ll = lane & 15;
    const int nt = 2 * qtb + 2;
    const int qwave = q0 + wid * 16;        // this wave's first q row

    // ---- Q fragments (registers) -----------------------------------------
    bf16x8 qf[6];
    {
        const bf16* qrow = Q + (size_t)(qwave + ll) * 6144 + h * 192;
#pragma unroll
        for (int dk = 0; dk < 6; ++dk)
            qf[dk] = *(const bf16x8*)(qrow + dk * 32 + lg * 8);
    }

    // ---- staging maps (computed once) ------------------------------------
    // Kn: 1024 chunks (64 rows x 16), 2 passes
    int knRow[2], knDst[2]; size_t knSrc[2];
    // Kp: 512 chunks (64 rows x 8), 1 pass
    int kpDst; size_t kpSrc;
    // Vt: 1024 chunks (128 rows x 8), 2 passes
    int vtDst[2]; size_t vtSrc[2];
#pragma unroll
    for (int p = 0; p < 2; ++p) {
        int f = tid + p * 512;
        int r = f >> 4, c = f & 15;
        knRow[p] = r;
        knDst[p] = r * 128 + ((c ^ (r & 7)) * 8);
        knSrc[p] = (size_t)r * 8192 + h * 256 + c * 8;
    }
    {
        int r = tid >> 3, c = tid & 7;
        kpDst = r * 64 + ((c ^ (r & 7)) * 8);
        kpSrc = (size_t)r * 64 + c * 8;
    }
#pragma unroll
    for (int p = 0; p < 2; ++p) {
        int f = tid + p * 512;
        int r = f >> 3, c = f & 7;
        vtDst[p] = r * 64 + ((c ^ (r & 7)) * 8);
        vtSrc[p] = (size_t)(h * 128 + r) * 2048 + c * 8;
    }

    bf16x8 rkn[2], rkp, rvt[2];
    // prologue: load tile 0
#pragma unroll
    for (int p = 0; p < 2; ++p) rkn[p] = *(const bf16x8*)(KV + knSrc[p]);
    rkp = *(const bf16x8*)(KPE + kpSrc);
#pragma unroll
    for (int p = 0; p < 2; ++p) rvt[p] = *(const bf16x8*)(VT + vtSrc[p]);

    f32x4 accO[8] = {};
    float m_r[4], l_r[4];
#pragma unroll
    for (int j = 0; j < 4; ++j) { m_r[j] = -INFINITY; l_r[j] = 0.f; }

    const int e7 = ll & 7;
    bf16* psW = psS + wid * 16 * 88;

    for (int kt = 0; kt < nt; ++kt) {
        const int k0 = kt * 64;
        __syncthreads();
        // ---- regs -> LDS (swizzled) --------------------------------------
#pragma unroll
        for (int p = 0; p < 2; ++p) *(bf16x8*)(knS + knDst[p]) = rkn[p];
        *(bf16x8*)(kpS + kpDst) = rkp;
#pragma unroll
        for (int p = 0; p < 2; ++p) *(bf16x8*)(vtS + vtDst[p]) = rvt[p];
        __syncthreads();
        // ---- issue next tile's global loads (overlap with compute) -------
        if (kt + 1 < nt) {
            const size_t kvo = (size_t)(k0 + 64) * 8192;
            const size_t kpo = (size_t)(k0 + 64) * 64;
#pragma unroll
            for (int p = 0; p < 2; ++p) rkn[p] = *(const bf16x8*)(KV + kvo + knSrc[p]);
            rkp = *(const bf16x8*)(KPE + kpo + kpSrc);
#pragma unroll
            for (int p = 0; p < 2; ++p) rvt[p] = *(const bf16x8*)(VT + (k0 + 64) + vtSrc[p]);
        }
        // ---- per-wave skip: tile entirely above causal diagonal ----------
        if (k0 > qwave + 15) continue;

        // ---- S = Q K^T ---------------------------------------------------
        f32x4 sacc[4] = {};
#pragma unroll
        for (int dk = 0; dk < 4; ++dk)
#pragma unroll
            for (int ni = 0; ni < 4; ++ni) {
                bf16x8 kf = *(const bf16x8*)(knS + (ni * 16 + ll) * 128 +
                                             (((dk * 4 + lg) ^ e7) * 8));
                sacc[ni] = __builtin_amdgcn_mfma_f32_16x16x32_bf16(qf[dk], kf, sacc[ni], 0, 0, 0);
            }
#pragma unroll
        for (int dk = 4; dk < 6; ++dk)
#pragma unroll
            for (int ni = 0; ni < 4; ++ni) {
                bf16x8 kf = *(const bf16x8*)(kpS + (ni * 16 + ll) * 64 +
                                             ((((dk - 4) * 4 + lg) ^ e7) * 8));
                sacc[ni] = __builtin_amdgcn_mfma_f32_16x16x32_bf16(qf[dk], kf, sacc[ni], 0, 0, 0);
            }

        // ---- mask + online softmax --------------------------------------
        float sv[4][4];
        const bool needm = (k0 + 63 > qwave);
#pragma unroll
        for (int ni = 0; ni < 4; ++ni)
#pragma unroll
            for (int j = 0; j < 4; ++j) {
                float s = sacc[ni][j];
                if (needm) {
                    int qg = qwave + lg * 4 + j;
                    int kg = k0 + ni * 16 + ll;
                    if (kg > qg) s = -3.0e38f;
                }
                sv[ni][j] = s;
            }
#pragma unroll
        for (int j = 0; j < 4; ++j) {
            float pm = fmaxf(fmaxf(sv[0][j], sv[1][j]), fmaxf(sv[2][j], sv[3][j]));
#pragma unroll
            for (int msk = 1; msk <= 8; msk <<= 1)
                pm = fmaxf(pm, __shfl_xor(pm, msk));
            float mn = fmaxf(m_r[j], pm);
            float al = __expf(m_r[j] - mn);
            float ps = 0.f;
#pragma unroll
            for (int ni = 0; ni < 4; ++ni) {
                float p = __expf(sv[ni][j] - mn);
                sv[ni][j] = p; ps += p;
            }
#pragma unroll
            for (int msk = 1; msk <= 8; msk <<= 1)
                ps += __shfl_xor(ps, msk);
            l_r[j] = l_r[j] * al + ps;
            m_r[j] = mn;
#pragma unroll
            for (int vt = 0; vt < 8; ++vt) accO[vt][j] *= al;
#pragma unroll
            for (int ni = 0; ni < 4; ++ni)
                psW[(lg * 4 + j) * 88 + ni * 16 + ll] = (bf16)sv[ni][j];
        }

        // ---- O += P V ----------------------------------------------------
        bf16x8 pa[2];
#pragma unroll
        for (int kb = 0; kb < 2; ++kb)
            pa[kb] = *(const bf16x8*)(psW + ll * 88 + kb * 32 + lg * 8);
#pragma unroll
        for (int vt = 0; vt < 8; ++vt)
#pragma unroll
            for (int kb = 0; kb < 2; ++kb) {
                bf16x8 vf = *(const bf16x8*)(vtS + (vt * 16 + ll) * 64 +
                                             (((kb * 4 + lg) ^ e7) * 8));
                accO[vt] = __builtin_amdgcn_mfma_f32_16x16x32_bf16(pa[kb], vf, accO[vt], 0, 0, 0);
            }
    }

    // ---- epilogue --------------------------------------------------------
    float inv[4];
#pragma unroll
    for (int j = 0; j < 4; ++j) inv[j] = 1.0f / l_r[j];
#pragma unroll
    for (int vt = 0; vt < 8; ++vt)
#pragma unroll
        for (int j = 0; j < 4; ++j) {
            int row = qwave + lg * 4 + j;
            O[(size_t)row * 4096 + h * 128 + vt * 16 + ll] = (bf16)(accO[vt][j] * inv[j]);
        }
}

// ---------------------------------------------------------------------------
extern "C" void kernel_launch(void* const* d_in, const int* in_sizes, int n_in,
                              void* d_out, int out_size, void* d_ws, size_t ws_size,
                              hipStream_t stream)
{
    (void)in_sizes; (void)n_in; (void)out_size; (void)ws_size;
    const float* hs    = (const float*)d_in[1];
    const float* w_qa  = (const float*)d_in[2];
    const float* w_kva = (const float*)d_in[3];
    const float* g_qa  = (const float*)d_in[4];
    const float* w_qb  = (const float*)d_in[5];
    const float* g_kva = (const float*)d_in[6];
    const float* w_kvb = (const float*)d_in[7];
    const float* w_o   = (const float*)d_in[8];
    float* out = (float*)d_out;

    // ---- workspace layout. Aliases (all lifetime-checked):
    //   qfin  over [hsb|wqaT]   (dead after GEMM2 / GEMM1)
    //   attnb over [q_c|kvraw]  (dead after rmsnorm / kvpost)
    //   Vtg   over wqbT         (dead after GEMM3; written by GEMM4)
    char* w = (char*)d_ws;
    bf16* hsb   = (bf16*)w;                     w += (size_t)2048 * 4096 * 2;
    bf16* wqaT  = (bf16*)w;                     w += (size_t)1536 * 4096 * 2;
    bf16* wkvaT = (bf16*)w;                     w += (size_t)640  * 4096 * 2;
    bf16* wqbT  = (bf16*)w;                     w += (size_t)6144 * 1536 * 2;
    bf16* wkvbT = (bf16*)w;                     w += (size_t)8192 * 512  * 2;
    bf16* woT   = (bf16*)w;                     w += (size_t)4096 * 4096 * 2;
    float* q_c  = (float*)w;                    w += (size_t)2048 * 1536 * 4;
    float* kvraw= (float*)w;                    w += (size_t)2048 * 576  * 4;
    bf16* q_cn  = (bf16*)w;                     w += (size_t)2048 * 1536 * 2;
    bf16* kv_cn = (bf16*)w;                     w += (size_t)2048 * 512  * 2;
    bf16* k_pe  = (bf16*)w;                     w += (size_t)2048 * 64   * 2;
    bf16* kvup  = (bf16*)w;                     w += (size_t)2048 * 8192 * 2;
    bf16* qfin  = hsb;
    bf16* attnb = (bf16*)q_c;
    bf16* Vtg   = wqbT;     // 4096*2048 bf16 = 16.78MB into wqbT's 18.87MB

    dim3 blk(256);
    cast_f32_bf16<<<8192, blk, 0, stream>>>(hs, hsb, 2048 * 4096);
    transpose_cast<<<dim3(48, 128),  blk, 0, stream>>>(w_qa,  wqaT,  4096, 1536);
    transpose_cast<<<dim3(20, 128),  blk, 0, stream>>>(w_kva, wkvaT, 4096, 576);
    transpose_cast<<<dim3(192, 48),  blk, 0, stream>>>(w_qb,  wqbT,  1536, 6144);
    transpose_cast<<<dim3(256, 16),  blk, 0, stream>>>(w_kvb, wkvbT, 512,  8192);
    transpose_cast<<<dim3(128, 128), blk, 0, stream>>>(w_o,   woT,   4096, 4096);

    gemm_bf16<0><<<dim3(12, 16), blk, 0, stream>>>(hsb, wqaT,  q_c,   nullptr, 2048, 1536, 4096);
    gemm_bf16<0><<<dim3(5,  16), blk, 0, stream>>>(hsb, wkvaT, kvraw, nullptr, 2048, 576,  4096);

    rmsnorm1536_bf16<<<2048, blk, 0, stream>>>(q_c, g_qa, q_cn);
    kvpost<<<2048, blk, 0, stream>>>(kvraw, g_kva, kv_cn, k_pe);

    gemm_bf16<1><<<dim3(48, 16), blk, 0, stream>>>(q_cn, wqbT, qfin, nullptr, 2048, 6144, 1536);
    qrope_scale<<<2048, blk, 0, stream>>>(qfin);

    // kvup: even N-blocks -> k_nope row-major in kvup; odd -> V^T into Vtg
    gemm_bf16<2><<<dim3(64, 16), blk, 0, stream>>>(kv_cn, wkvbT, kvup, Vtg, 2048, 8192, 512);

    attn_mfma<<<dim3(16, 32), dim3(512), 0, stream>>>(qfin, kvup, k_pe, Vtg, attnb);

    gemm_bf16<0><<<dim3(32, 16), blk, 0, stream>>>(attnb, woT, out, nullptr, 2048, 4096, 4096);
}